// Round 1
// baseline (656.499 us; speedup 1.0000x reference)
//
#include <hip/hip_runtime.h>
#include <stdint.h>

#define N_    512
#define C_    128
#define NN_   (N_ * N_)           // 262144
#define ROWS_ (2 * NN_)           // 524288
#define GATE_ ((long)2 * 8 * NN_) // 4194304 elems per gate buffer

typedef __attribute__((ext_vector_type(8))) short short8;
typedef __attribute__((ext_vector_type(4))) float f32x4;

static __device__ __forceinline__ unsigned short f2bf(float f) {
    union { float f; unsigned u; } v; v.f = f;
    unsigned r = v.u + 0x7fffu + ((v.u >> 16) & 1u);
    return (unsigned short)(r >> 16);
}
static __device__ __forceinline__ float bf2f(unsigned short h) {
    union { unsigned u; float f; } v; v.u = ((unsigned)h) << 16;
    return v.f;
}
static __device__ __forceinline__ float sigmoidf_(float x) {
    return __builtin_amdgcn_rcpf(1.0f + __expf(-x));
}

// ---------------------------------------------------------------------------
// Kernel 1: LayerNorm + dual projection (Wv,We) + mask + siglin gating.
// Block = 256 threads (4 waves), 64 rows of e per block; wave w owns rows
// w*16 .. w*16+15 register-resident (lane l&15 = row, l>>4 = col-quad).
// GEMM: [64 x 128] @ [128 x 64] via mfma_f32_16x16x32_bf16; W staged in LDS
// in fragment order (one ds_read_b128 per B-fragment).
// Gate outputs stored bf16 as [B][H][N][N] (first spatial index major) so the
// "in" einsum reads k-minor (NT) and the "out" einsum reads k-major (TN).
// ---------------------------------------------------------------------------
__global__ __launch_bounds__(256) void k_lnproj(
    const float* __restrict__ e, const float* __restrict__ mask,
    const float* __restrict__ lnw, const float* __restrict__ lnb,
    const float* __restrict__ Wv, const float* __restrict__ bv,
    const float* __restrict__ We, const float* __restrict__ be,
    unsigned short* __restrict__ Vin, unsigned short* __restrict__ Vout,
    unsigned short* __restrict__ Ein, unsigned short* __restrict__ Eout)
{
    __shared__ __align__(16) unsigned short ldsW[16 * 64 * 8]; // frag-order, 16 KB
    const int t = threadIdx.x;
    const int w = t >> 6, l = t & 63;
    const int l15 = l & 15, q = l >> 4;
    const long R0 = (long)blockIdx.x * 64;

    // Stage concat(Wv, We) -> LDS in MFMA B-fragment order.
    // chunk = kc*4 + ct; within chunk: lane li, 8 bf16 (j) contiguous.
#pragma unroll
    for (int g = 0; g < 4; ++g) {
        int fragidx = t * 4 + g;          // 0..1023
        int chunk = fragidx >> 6, li = fragidx & 63;
        int kc = chunk >> 2, ct = chunk & 3;
        int qq = li >> 4, nn = li & 15;
        int c = ct * 16 + nn;             // 0..63: 0..31 -> Wv, 32..63 -> We
        short8 v;
#pragma unroll
        for (int j = 0; j < 8; ++j) {
            int k = kc * 32 + qq * 8 + j;
            float wv = (c < 32) ? Wv[k * 32 + c] : We[k * 32 + (c - 32)];
            v[j] = (short)f2bf(wv);
        }
        *(short8*)(&ldsW[fragidx * 8]) = v;
    }

    // Load this lane's 32 e-values (cols kc*32 + q*8 + j), coalesced.
    const long Rg = R0 + w * 16 + l15;
    const float* erow = e + Rg * C_ + q * 8;
    float x[32];
#pragma unroll
    for (int kc = 0; kc < 4; ++kc) {
        float4 a = *(const float4*)(erow + kc * 32);
        float4 b = *(const float4*)(erow + kc * 32 + 4);
        x[kc*8+0] = a.x; x[kc*8+1] = a.y; x[kc*8+2] = a.z; x[kc*8+3] = a.w;
        x[kc*8+4] = b.x; x[kc*8+5] = b.y; x[kc*8+6] = b.z; x[kc*8+7] = b.w;
    }
    // Row stats: lanes {l15, l15+16, l15+32, l15+48} hold the same row.
    float s = 0.f, s2 = 0.f;
#pragma unroll
    for (int i = 0; i < 32; ++i) { s += x[i]; s2 += x[i] * x[i]; }
    s  += __shfl_xor(s, 16);  s2 += __shfl_xor(s2, 16);
    s  += __shfl_xor(s, 32);  s2 += __shfl_xor(s2, 32);
    float mu   = s * (1.f / 128.f);
    float var  = s2 * (1.f / 128.f) - mu * mu;
    float rstd = rsqrtf(var + 1e-5f);

    // Build bf16 A-fragments: A[m = l&15][k = (l>>4)*8 + j]
    short8 af[4];
#pragma unroll
    for (int kc = 0; kc < 4; ++kc) {
#pragma unroll
        for (int j = 0; j < 8; ++j) {
            int k = kc * 32 + q * 8 + j;
            float v = (x[kc*8+j] - mu) * rstd * lnw[k] + lnb[k];
            af[kc][j] = (short)f2bf(v);
        }
    }
    __syncthreads();

    f32x4 acc[4];
#pragma unroll
    for (int ct = 0; ct < 4; ++ct) acc[ct] = (f32x4){0.f, 0.f, 0.f, 0.f};
#pragma unroll
    for (int kc = 0; kc < 4; ++kc) {
#pragma unroll
        for (int ct = 0; ct < 4; ++ct) {
            short8 bf = *(const short8*)(&ldsW[((kc * 4 + ct) * 64 + l) * 8]);
            acc[ct] = __builtin_amdgcn_mfma_f32_16x16x32_bf16(af[kc], bf, acc[ct], 0, 0, 0);
        }
    }

    // Epilogue: C[row=(l>>4)*4+reg][col=16*ct+l15]; col pairs (c, c+8) are
    // (gate, linear) -> shfl_xor(8). ct: 0=V_in 1=V_out 2=E_in 3=E_out.
    float mrow[4];
#pragma unroll
    for (int r = 0; r < 4; ++r) mrow[r] = mask[R0 + w * 16 + q * 4 + r];
    const bool is_gate = (l15 & 8) == 0;
    const int h = l15 & 7;
    unsigned short* bufs[4] = { Vin, Vout, Ein, Eout };
#pragma unroll
    for (int ct = 0; ct < 4; ++ct) {
        int cc = (ct * 16 + l15) & 31;
        float bias = (ct < 2) ? bv[cc] : be[cc];
#pragma unroll
        for (int r = 0; r < 4; ++r) {
            float val = acc[ct][r] + bias;
            float partner = __shfl_xor(val, 8);   // all lanes execute
            if (is_gate) {
                long Rc = R0 + w * 16 + q * 4 + r;
                float res = partner * sigmoidf_(val + mrow[r]);
                long bb  = Rc >> 18;          // / NN_
                long rem = Rc & (NN_ - 1);    // i*N + j
                bufs[ct][(bb * 8 + h) * (long)NN_ + rem] = f2bf(res);
            }
        }
    }
}

// ---------------------------------------------------------------------------
// Kernel 2: 32 batched N x N x N GEMMs (per b, h, flavor).
//  flavor 0 ("in"):  C[i,j] = sum_k Ein[i,k] * Vin[j,k]   (both k-minor, NT)
//  flavor 1 ("out"): C[i,j] = sum_k Eout[k,i] * Vout[k,j] (both k-major, TN;
//                    transposed at LDS-staging so inner loop is identical)
// Block: 64x64 C-tile, 4 waves of 32x32 (2x2 16x16 tiles), K-step 64.
// LDS tiles [64][72] bf16 (pad 8 keeps b128 frag reads bank-even & aligned).
// Output Va bf16, layout [B][16][N][N], ch = flavor*8 + h.
// ---------------------------------------------------------------------------
__global__ __launch_bounds__(256) void k_tri(
    const unsigned short* __restrict__ Vin, const unsigned short* __restrict__ Vout,
    const unsigned short* __restrict__ Ein, const unsigned short* __restrict__ Eout,
    unsigned short* __restrict__ Va)
{
    __shared__ __align__(16) unsigned short lA[64 * 72];
    __shared__ __align__(16) unsigned short lB[64 * 72];
    const int bid = blockIdx.x;
    const int tj = bid & 7, ti = (bid >> 3) & 7, fl = (bid >> 6) & 1;
    const int h = (bid >> 7) & 7, b = (bid >> 10) & 1;
    const unsigned short* Ap = (fl ? Eout : Ein) + (long)(b * 8 + h) * NN_;
    const unsigned short* Bp = (fl ? Vout : Vin) + (long)(b * 8 + h) * NN_;
    unsigned short* Cp = Va + (long)(b * 16 + fl * 8 + h) * NN_;

    const int t = threadIdx.x;
    const int w = t >> 6, l = t & 63, l15 = l & 15, q = l >> 4;
    const int rt2 = (w >> 1) * 32, ct2 = (w & 1) * 32;

    f32x4 acc[2][2];
#pragma unroll
    for (int rr = 0; rr < 2; ++rr)
#pragma unroll
        for (int cc = 0; cc < 2; ++cc) acc[rr][cc] = (f32x4){0.f, 0.f, 0.f, 0.f};

    for (int ks = 0; ks < 512; ks += 64) {
        if (fl == 0) {
            // NT: rows are i/j, k-minor: straight 16B copies.
#pragma unroll
            for (int p = 0; p < 2; ++p) {
                int cid = t + p * 256;
                int r = cid >> 3, seg = cid & 7;
                *(uint4*)(&lA[r * 72 + seg * 8]) =
                    *(const uint4*)(Ap + (long)(ti * 64 + r) * 512 + ks + seg * 8);
                *(uint4*)(&lB[r * 72 + seg * 8]) =
                    *(const uint4*)(Bp + (long)(tj * 64 + r) * 512 + ks + seg * 8);
            }
        } else {
            // TN: global rows are k; transpose into [i][k] at staging.
#pragma unroll
            for (int p = 0; p < 2; ++p) {
                int cid = t + p * 256;
                int kr = cid >> 3, seg = cid & 7;
                uint4 va = *(const uint4*)(Ap + (long)(ks + kr) * 512 + ti * 64 + seg * 8);
                uint4 vb = *(const uint4*)(Bp + (long)(ks + kr) * 512 + tj * 64 + seg * 8);
                const unsigned short* pa = (const unsigned short*)&va;
                const unsigned short* pb = (const unsigned short*)&vb;
#pragma unroll
                for (int j2 = 0; j2 < 8; ++j2) {
                    lA[(seg * 8 + j2) * 72 + kr] = pa[j2];
                    lB[(seg * 8 + j2) * 72 + kr] = pb[j2];
                }
            }
        }
        __syncthreads();
#pragma unroll
        for (int kc = 0; kc < 64; kc += 32) {
            short8 a0 = *(const short8*)(&lA[(rt2      + l15) * 72 + kc + q * 8]);
            short8 a1 = *(const short8*)(&lA[(rt2 + 16 + l15) * 72 + kc + q * 8]);
            short8 b0 = *(const short8*)(&lB[(ct2      + l15) * 72 + kc + q * 8]);
            short8 b1 = *(const short8*)(&lB[(ct2 + 16 + l15) * 72 + kc + q * 8]);
            acc[0][0] = __builtin_amdgcn_mfma_f32_16x16x32_bf16(a0, b0, acc[0][0], 0, 0, 0);
            acc[0][1] = __builtin_amdgcn_mfma_f32_16x16x32_bf16(a0, b1, acc[0][1], 0, 0, 0);
            acc[1][0] = __builtin_amdgcn_mfma_f32_16x16x32_bf16(a1, b0, acc[1][0], 0, 0, 0);
            acc[1][1] = __builtin_amdgcn_mfma_f32_16x16x32_bf16(a1, b1, acc[1][1], 0, 0, 0);
        }
        __syncthreads();
    }
#pragma unroll
    for (int rr = 0; rr < 2; ++rr)
#pragma unroll
        for (int cc = 0; cc < 2; ++cc)
#pragma unroll
            for (int r = 0; r < 4; ++r) {
                int row = ti * 64 + rt2 + rr * 16 + q * 4 + r;
                int col = tj * 64 + ct2 + cc * 16 + l15;
                Cp[(long)row * 512 + col] = f2bf(acc[rr][cc][r]);
            }
}

// ---------------------------------------------------------------------------
// Kernel 3: O = Va @ Wo + bo; out = sigmoid(O[:, :128]) * O[:, 128:].
// Block = 64 rows; Wo/bo/Va tile in LDS; per-thread dual dot-16 (weights
// hoisted to registers, Va reads are wave-broadcast). Coalesced fp32 stores.
// ---------------------------------------------------------------------------
__global__ __launch_bounds__(256) void k_out(
    const unsigned short* __restrict__ Va,
    const float* __restrict__ Wo, const float* __restrict__ bo,
    float* __restrict__ out)
{
    __shared__ __align__(16) float lWo[16 * 256];
    __shared__ float lbo[256];
    __shared__ float lVa[64 * 16];
    const int t = threadIdx.x;
    const long R0 = (long)blockIdx.x * 64;
    const long bb = R0 >> 18;
    const long rem0 = R0 & (NN_ - 1);
#pragma unroll
    for (int i = 0; i < 4; ++i) {
        int idx = t + i * 256;
        *(float4*)(&lWo[idx * 4]) = *(const float4*)(Wo + idx * 4);
    }
    lbo[t] = bo[t];
    {
        int ch = t >> 4;
        int p = (t & 15) * 4;
        const unsigned short* src = Va + (bb * 16 + ch) * (long)NN_ + rem0 + p;
        uint2 v = *(const uint2*)src;
        const unsigned short* pu = (const unsigned short*)&v;
#pragma unroll
        for (int i = 0; i < 4; ++i) lVa[(p + i) * 16 + ch] = bf2f(pu[i]);
    }
    __syncthreads();
    const int c = t & 127;
    const int rb = t >> 7;
    float wg[16], wl[16];
#pragma unroll
    for (int u = 0; u < 16; ++u) {
        wg[u] = lWo[u * 256 + c];
        wl[u] = lWo[u * 256 + 128 + c];
    }
    const float bg = lbo[c], bl = lbo[128 + c];
    for (int it = 0; it < 32; ++it) {
        int r = it * 2 + rb;
        float gacc = bg, lacc = bl;
#pragma unroll
        for (int u = 0; u < 16; ++u) {
            float a = lVa[r * 16 + u];
            gacc += a * wg[u];
            lacc += a * wl[u];
        }
        out[(R0 + r) * 128 + c] = lacc * sigmoidf_(gacc);
    }
}

// ---------------------------------------------------------------------------
extern "C" void kernel_launch(void* const* d_in, const int* in_sizes, int n_in,
                              void* d_out, int out_size, void* d_ws, size_t ws_size,
                              hipStream_t stream)
{
    const float* e    = (const float*)d_in[0];
    const float* mask = (const float*)d_in[1];
    const float* lnw  = (const float*)d_in[2];
    const float* lnb  = (const float*)d_in[3];
    const float* Wv   = (const float*)d_in[4];
    const float* bv   = (const float*)d_in[5];
    const float* We   = (const float*)d_in[6];
    const float* be   = (const float*)d_in[7];
    const float* Wo   = (const float*)d_in[8];
    const float* bo   = (const float*)d_in[9];
    float* out = (float*)d_out;

    // Workspace (bf16): 4 gate buffers + Va = 48 MB total.
    unsigned short* ws   = (unsigned short*)d_ws;
    unsigned short* Ein  = ws;
    unsigned short* Vin  = ws + 1L * GATE_;
    unsigned short* Eout = ws + 2L * GATE_;
    unsigned short* Vout = ws + 3L * GATE_;
    unsigned short* Va   = ws + 4L * GATE_;

    hipLaunchKernelGGL(k_lnproj, dim3(ROWS_ / 64), dim3(256), 0, stream,
                       e, mask, lnw, lnb, Wv, bv, We, be, Vin, Vout, Ein, Eout);
    hipLaunchKernelGGL(k_tri, dim3(2048), dim3(256), 0, stream,
                       Vin, Vout, Ein, Eout, Va);
    hipLaunchKernelGGL(k_out, dim3(ROWS_ / 64), dim3(256), 0, stream,
                       Va, Wo, bo, out);
}

// Round 2
// 511.534 us; speedup vs baseline: 1.2834x; 1.2834x over previous
//
#include <hip/hip_runtime.h>
#include <stdint.h>

#define N_    512
#define C_    128
#define NN_   (N_ * N_)           // 262144
#define ROWS_ (2 * NN_)           // 524288
#define GATE_ ((long)2 * 8 * NN_) // 4194304 elems per gate buffer (bf16)

typedef __attribute__((ext_vector_type(8))) short short8;
typedef __attribute__((ext_vector_type(4))) float f32x4;
typedef __attribute__((ext_vector_type(4))) unsigned uint4_t;
typedef __attribute__((ext_vector_type(2))) unsigned uint2_t;
typedef unsigned short u16;

static __device__ __forceinline__ u16 f2bf(float f) {
    union { float f; unsigned u; } v; v.f = f;
    unsigned r = v.u + 0x7fffu + ((v.u >> 16) & 1u);
    return (u16)(r >> 16);
}
static __device__ __forceinline__ float bf2f(u16 h) {
    union { unsigned u; float f; } v; v.u = ((unsigned)h) << 16;
    return v.f;
}
static __device__ __forceinline__ float sigmoidf_(float x) {
    return __builtin_amdgcn_rcpf(1.0f + __expf(-x));
}

// ---------------------------------------------------------------------------
// k_prep: build MFMA-fragment-ordered bf16 weight tables in global ws.
//  WB  [1024 groups x 8]: concat(Wv,We) B-frags. group = (kc*4+ct)*64 + lane;
//      elem j: k = kc*32 + (lane>>4)*8 + j, col c = ct*16 + (lane&15);
//      c<32 -> Wv[k][c], else We[k][c-32].
//  WoB [2048 groups x 8]: Wo B-frags (hi part then lo part), K padded 16->32.
//      group = part*1024 + ct*64 + lane; elem j: k = (lane>>4)*8+j,
//      col = ct*16 + (lane&15); k<16 -> Wo[k][col] split hi/lo, else 0.
// ---------------------------------------------------------------------------
__global__ __launch_bounds__(256) void k_prep(
    const float* __restrict__ Wv, const float* __restrict__ We,
    const float* __restrict__ Wo, u16* __restrict__ WB, u16* __restrict__ WoB)
{
    int gid = blockIdx.x * 256 + threadIdx.x;
    if (gid < 1024) {
        int chunk = gid >> 6, li = gid & 63;
        int kc = chunk >> 2, ct = chunk & 3;
        int qq = li >> 4, nn = li & 15, c = ct * 16 + nn;
        short8 v;
#pragma unroll
        for (int j = 0; j < 8; ++j) {
            int k = kc * 32 + qq * 8 + j;
            float w = (c < 32) ? Wv[k * 32 + c] : We[k * 32 + (c - 32)];
            v[j] = (short)f2bf(w);
        }
        *(short8*)(&WB[gid * 8]) = v;
    } else if (gid < 3072) {
        int g = gid - 1024;
        int ctp = g >> 6, li = g & 63;
        int ct = ctp & 15, part = ctp >> 4;
        int qq = li >> 4, nn = li & 15, col = ct * 16 + nn;
        short8 v;
#pragma unroll
        for (int j = 0; j < 8; ++j) {
            int k = qq * 8 + j;
            if (k < 16) {
                float w = Wo[k * 256 + col];
                u16 hi = f2bf(w);
                v[j] = part ? (short)f2bf(w - bf2f(hi)) : (short)hi;
            } else v[j] = 0;
        }
        *(short8*)(&WoB[g * 8]) = v;
    }
}

// ---------------------------------------------------------------------------
// k_lnproj: LN + dual projection + mask + siglin. No LDS, no barrier.
// Block = 256 (4 waves), 64 e-rows/block, wave w owns rows w*16..w*16+15.
// B-frags come straight from the hot 16KB WB table (L1/L2 resident).
// Gate outputs bf16 [B][H][N][N]; 4 packed 8B stores per thread.
// ---------------------------------------------------------------------------
__global__ __launch_bounds__(256) void k_lnproj(
    const float* __restrict__ e, const float* __restrict__ mask,
    const float* __restrict__ lnw, const float* __restrict__ lnb,
    const float* __restrict__ bv, const float* __restrict__ be,
    const u16* __restrict__ WB,
    u16* __restrict__ Vin, u16* __restrict__ Vout,
    u16* __restrict__ Ein, u16* __restrict__ Eout)
{
    const int t = threadIdx.x;
    const int w = t >> 6, l = t & 63;
    const int l15 = l & 15, q = l >> 4;
    const long R0 = (long)blockIdx.x * 64;

    // Load this lane's 32 e-values (cols kc*32 + q*8 + j).
    const long Rg = R0 + w * 16 + l15;
    const float* erow = e + Rg * C_ + q * 8;
    float x[32];
#pragma unroll
    for (int kc = 0; kc < 4; ++kc) {
        float4 a = *(const float4*)(erow + kc * 32);
        float4 b = *(const float4*)(erow + kc * 32 + 4);
        x[kc*8+0] = a.x; x[kc*8+1] = a.y; x[kc*8+2] = a.z; x[kc*8+3] = a.w;
        x[kc*8+4] = b.x; x[kc*8+5] = b.y; x[kc*8+6] = b.z; x[kc*8+7] = b.w;
    }
    float s = 0.f, s2 = 0.f;
#pragma unroll
    for (int i = 0; i < 32; ++i) { s += x[i]; s2 += x[i] * x[i]; }
    s  += __shfl_xor(s, 16);  s2 += __shfl_xor(s2, 16);
    s  += __shfl_xor(s, 32);  s2 += __shfl_xor(s2, 32);
    float mu   = s * (1.f / 128.f);
    float var  = s2 * (1.f / 128.f) - mu * mu;
    float rstd = rsqrtf(var + 1e-5f);

    short8 af[4];
#pragma unroll
    for (int kc = 0; kc < 4; ++kc) {
        const float* lwp = lnw + kc * 32 + q * 8;
        const float* lbp = lnb + kc * 32 + q * 8;
        float4 w0 = *(const float4*)lwp, w1 = *(const float4*)(lwp + 4);
        float4 b0 = *(const float4*)lbp, b1 = *(const float4*)(lbp + 4);
        float ww[8] = {w0.x,w0.y,w0.z,w0.w,w1.x,w1.y,w1.z,w1.w};
        float bb[8] = {b0.x,b0.y,b0.z,b0.w,b1.x,b1.y,b1.z,b1.w};
#pragma unroll
        for (int j = 0; j < 8; ++j)
            af[kc][j] = (short)f2bf((x[kc*8+j] - mu) * rstd * ww[j] + bb[j]);
    }

    f32x4 acc[4];
#pragma unroll
    for (int ct = 0; ct < 4; ++ct) acc[ct] = (f32x4){0.f, 0.f, 0.f, 0.f};
#pragma unroll
    for (int kc = 0; kc < 4; ++kc) {
#pragma unroll
        for (int ct = 0; ct < 4; ++ct) {
            short8 bf = *(const short8*)(WB + ((kc * 4 + ct) * 64 + l) * 8);
            acc[ct] = __builtin_amdgcn_mfma_f32_16x16x32_bf16(af[kc], bf, acc[ct], 0, 0, 0);
        }
    }

    // Epilogue. C[row=q*4+r][col=ct*16+l15]; (c, c+8) = (gate, linear).
    float mrow[4];
#pragma unroll
    for (int r = 0; r < 4; ++r) mrow[r] = mask[R0 + w * 16 + q * 4 + r];
    const bool is_gate = (l15 & 8) == 0;
    const int h = l15 & 7;
    const long bb_ = R0 >> 18;
    const long rem0 = (R0 & (NN_ - 1)) + w * 16 + q * 4;
    u16* bufs[4] = { Vin, Vout, Ein, Eout };
#pragma unroll
    for (int ct = 0; ct < 4; ++ct) {
        int cc = (ct * 16 + l15) & 31;
        float bias = (ct < 2) ? bv[cc] : be[cc];
        float vals[4];
#pragma unroll
        for (int r = 0; r < 4; ++r) {
            float val = acc[ct][r] + bias;
            float partner = __shfl_xor(val, 8);   // all lanes execute
            vals[r] = partner * sigmoidf_(val + mrow[r]);
        }
        if (is_gate) {
            uint2_t p;
            p[0] = (unsigned)f2bf(vals[0]) | ((unsigned)f2bf(vals[1]) << 16);
            p[1] = (unsigned)f2bf(vals[2]) | ((unsigned)f2bf(vals[3]) << 16);
            *(uint2_t*)(bufs[ct] + (bb_ * 8 + h) * (long)NN_ + rem0) = p;
        }
    }
}

// ---------------------------------------------------------------------------
// k_tri: 32 batched 512^3 GEMMs. 128x128 C-tile/block, 4 waves of 64x64
// (4x4 16x16 accs), BK=64. fl=0 (NT): straight b128 staging. fl=1 (TN):
// in-register 8x8 bf16 transpose (v_perm) then b128 LDS writes.
// LDS stride 72 shorts (pad 8) keeps frag reads 2-way-cheap.
// Output Va bf16 [B][16][N][N], ch = fl*8 + h.
// ---------------------------------------------------------------------------
__global__ __launch_bounds__(256) void k_tri(
    const u16* __restrict__ Vin, const u16* __restrict__ Vout,
    const u16* __restrict__ Ein, const u16* __restrict__ Eout,
    u16* __restrict__ Va)
{
    __shared__ __align__(16) u16 lA[128 * 72];
    __shared__ __align__(16) u16 lB[128 * 72];
    const int bid = blockIdx.x;
    const int tj = bid & 3, ti = (bid >> 2) & 3, fl = (bid >> 4) & 1;
    const int h = (bid >> 5) & 7, b = (bid >> 8) & 1;
    const u16* Ap = (fl ? Eout : Ein) + (long)(b * 8 + h) * NN_;
    const u16* Bp = (fl ? Vout : Vin) + (long)(b * 8 + h) * NN_;
    u16* Cp = Va + (long)(b * 16 + fl * 8 + h) * NN_;

    const int t = threadIdx.x;
    const int w = t >> 6, l = t & 63, l15 = l & 15, q = l >> 4;
    const int rt = (w >> 1) * 64, ctl = (w & 1) * 64;

    f32x4 acc[4][4];
#pragma unroll
    for (int rr = 0; rr < 4; ++rr)
#pragma unroll
        for (int cc = 0; cc < 4; ++cc) acc[rr][cc] = (f32x4){0.f, 0.f, 0.f, 0.f};

    for (int ks = 0; ks < 512; ks += 64) {
        if (fl == 0) {
#pragma unroll
            for (int p = 0; p < 4; ++p) {
                int cid = t + p * 256;
                int r = cid >> 3, seg = cid & 7;
                *(uint4_t*)(&lA[r * 72 + seg * 8]) =
                    *(const uint4_t*)(Ap + (long)(ti * 128 + r) * 512 + ks + seg * 8);
                *(uint4_t*)(&lB[r * 72 + seg * 8]) =
                    *(const uint4_t*)(Bp + (long)(tj * 128 + r) * 512 + ks + seg * 8);
            }
        } else {
            // Transpose staging: thread owns one 8x8 block (i x k).
            const u16* P = (t < 128) ? Ap : Bp;
            u16* L = (t < 128) ? lA : lB;
            const int tt = t & 127, ib = tt & 15, kb = tt >> 4;  // ib:0..15, kb:0..7
            const int io = ((t < 128) ? ti : tj) * 128 + ib * 8;
            uint4_t o[8];
#pragma unroll
            for (int p2 = 0; p2 < 4; ++p2) {
                uint4_t ra = *(const uint4_t*)(P + (long)(ks + kb * 8 + 2 * p2    ) * 512 + io);
                uint4_t rb = *(const uint4_t*)(P + (long)(ks + kb * 8 + 2 * p2 + 1) * 512 + io);
#pragma unroll
                for (int d = 0; d < 4; ++d) {
                    o[2*d  ][p2] = __builtin_amdgcn_perm(rb[d], ra[d], 0x05040100u);
                    o[2*d+1][p2] = __builtin_amdgcn_perm(rb[d], ra[d], 0x07060302u);
                }
            }
#pragma unroll
            for (int j = 0; j < 8; ++j)
                *(uint4_t*)(&L[(ib * 8 + j) * 72 + kb * 8]) = o[j];
        }
        __syncthreads();
#pragma unroll
        for (int kf = 0; kf < 2; ++kf) {
            short8 a[4], bf[4];
#pragma unroll
            for (int rr = 0; rr < 4; ++rr)
                a[rr] = *(const short8*)(&lA[(rt + rr * 16 + l15) * 72 + kf * 32 + q * 8]);
#pragma unroll
            for (int cc = 0; cc < 4; ++cc)
                bf[cc] = *(const short8*)(&lB[(ctl + cc * 16 + l15) * 72 + kf * 32 + q * 8]);
#pragma unroll
            for (int rr = 0; rr < 4; ++rr)
#pragma unroll
                for (int cc = 0; cc < 4; ++cc)
                    acc[rr][cc] = __builtin_amdgcn_mfma_f32_16x16x32_bf16(a[rr], bf[cc], acc[rr][cc], 0, 0, 0);
        }
        __syncthreads();
    }
#pragma unroll
    for (int rr = 0; rr < 4; ++rr)
#pragma unroll
        for (int cc = 0; cc < 4; ++cc)
#pragma unroll
            for (int r = 0; r < 4; ++r) {
                int row = ti * 128 + rt + rr * 16 + q * 4 + r;
                int col = tj * 128 + ctl + cc * 16 + l15;
                Cp[(long)row * 512 + col] = f2bf(acc[rr][cc][r]);
            }
}

// ---------------------------------------------------------------------------
// k_out: O = Va @ Wo + bo (MFMA, K=16 padded to 32, Wo split hi+lo bf16);
// out = sigmoid(O[:, :128]) * O[:, 128:]. Block = 64 rows, 4 waves each
// computing 16 rows x 256 cols (16 acc tiles). Coalesced fp32 stores.
// ---------------------------------------------------------------------------
__global__ __launch_bounds__(256) void k_out(
    const u16* __restrict__ Va, const u16* __restrict__ WoB,
    const float* __restrict__ bo, float* __restrict__ out)
{
    __shared__ __align__(16) u16 lWoB[2048 * 8];   // 32 KB (hi then lo)
    __shared__ __align__(16) u16 lVa[64 * 32];     // 4 KB, k padded to 32
    const int t = threadIdx.x;
    const int w = t >> 6, l = t & 63, l15 = l & 15, q = l >> 4;
    const long R0 = (long)blockIdx.x * 64;
    const long bb = R0 >> 18;
    const long rem0 = R0 & (NN_ - 1);

#pragma unroll
    for (int i2 = 0; i2 < 8; ++i2)
        ((uint4_t*)lWoB)[i2 * 256 + t] = ((const uint4_t*)WoB)[i2 * 256 + t];
    {   // zero-pad k=16..31 of lVa
        int p = t >> 2, j4 = (t & 3) * 4;
        uint2_t z; z[0] = 0; z[1] = 0;
        *(uint2_t*)(&lVa[p * 32 + 16 + j4]) = z;
    }
    {   // stage Va rows (16 ch-planes, 4 rows per thread)
        int ch = t >> 4, p0 = (t & 15) * 4;
        uint2_t v = *(const uint2_t*)(Va + (bb * 16 + ch) * (long)NN_ + rem0 + p0);
        u16* pv = (u16*)&v;
#pragma unroll
        for (int i = 0; i < 4; ++i) lVa[(p0 + i) * 32 + ch] = pv[i];
    }
    __syncthreads();

    short8 af = *(const short8*)(&lVa[(w * 16 + l15) * 32 + q * 8]);
    f32x4 acc[16];
#pragma unroll
    for (int ct = 0; ct < 16; ++ct) acc[ct] = (f32x4){0.f, 0.f, 0.f, 0.f};
#pragma unroll
    for (int ct = 0; ct < 16; ++ct) {
        short8 bh = *(const short8*)(&lWoB[(ct * 64 + l) * 8]);
        short8 blo = *(const short8*)(&lWoB[((16 + ct) * 64 + l) * 8]);
        acc[ct] = __builtin_amdgcn_mfma_f32_16x16x32_bf16(af, bh, acc[ct], 0, 0, 0);
        acc[ct] = __builtin_amdgcn_mfma_f32_16x16x32_bf16(af, blo, acc[ct], 0, 0, 0);
    }

#pragma unroll
    for (int ct = 0; ct < 8; ++ct) {
        int cg = ct * 16 + l15;
        float bg = bo[cg], bl = bo[128 + cg];
#pragma unroll
        for (int r = 0; r < 4; ++r) {
            int row = w * 16 + q * 4 + r;
            float g  = acc[ct][r] + bg;
            float lv = acc[ct + 8][r] + bl;
            out[(R0 + row) * 128 + cg] = lv * sigmoidf_(g);
        }
    }
}

// ---------------------------------------------------------------------------
extern "C" void kernel_launch(void* const* d_in, const int* in_sizes, int n_in,
                              void* d_out, int out_size, void* d_ws, size_t ws_size,
                              hipStream_t stream)
{
    const float* e    = (const float*)d_in[0];
    const float* mask = (const float*)d_in[1];
    const float* lnw  = (const float*)d_in[2];
    const float* lnb  = (const float*)d_in[3];
    const float* Wv   = (const float*)d_in[4];
    const float* bv   = (const float*)d_in[5];
    const float* We   = (const float*)d_in[6];
    const float* be   = (const float*)d_in[7];
    const float* Wo   = (const float*)d_in[8];
    const float* bo   = (const float*)d_in[9];
    float* out = (float*)d_out;

    // ws (bf16 elems): 4 gate buffers + Va (2*GATE_) + WB(8K) + WoB(16K)
    u16* ws   = (u16*)d_ws;
    u16* Ein  = ws;
    u16* Vin  = ws + 1L * GATE_;
    u16* Eout = ws + 2L * GATE_;
    u16* Vout = ws + 3L * GATE_;
    u16* Va   = ws + 4L * GATE_;
    u16* WB   = ws + 6L * GATE_;
    u16* WoB  = WB + 8192;

    hipLaunchKernelGGL(k_prep, dim3(12), dim3(256), 0, stream, Wv, We, Wo, WB, WoB);
    hipLaunchKernelGGL(k_lnproj, dim3(ROWS_ / 64), dim3(256), 0, stream,
                       e, mask, lnw, lnb, bv, be, WB, Vin, Vout, Ein, Eout);
    hipLaunchKernelGGL(k_tri, dim3(512), dim3(256), 0, stream,
                       Vin, Vout, Ein, Eout, Va);
    hipLaunchKernelGGL(k_out, dim3(ROWS_ / 64), dim3(256), 0, stream,
                       Va, WoB, bo, out);
}